// Round 11
// baseline (323.653 us; speedup 1.0000x reference)
//
#include <hip/hip_runtime.h>
#include <math.h>

#define B_ 8
#define T_ 64
#define N_ 196
#define D_ 768
#define K_ 8
#define FEAT 40
#define EPSF 1e-6f

constexpr int BN = B_ * N_;                        // 1568
constexpr int ROWS = B_ * T_ * N_;                 // 100352
constexpr long long HSIZE = (long long)ROWS * D_;  // 77070336
constexpr int QPR = D_ / 4;                        // 192 float4 per row
constexpr unsigned RSTRIDE = (unsigned)N_ * QPR;   // 37632 v4f per t-step

typedef float v4f __attribute__((ext_vector_type(4)));

__device__ __forceinline__ float wredux(float v) {
#pragma unroll
    for (int off = 32; off > 0; off >>= 1)
        v += __shfl_xor(v, off, 64);
    return v;
}

__device__ __forceinline__ float dot4(v4f a, v4f b) {
    return a.x * b.x + a.y * b.y + a.z * b.z + a.w * b.w;
}

__device__ __forceinline__ float softplusf(float xw) {
    return fmaxf(xw, 0.0f) + log1pf(expf(-fabsf(xw)));
}

// Single fused kernel. Blocks 0..BN-1: one (b,n) column each, 4 waves.
// Block BN: writes W = softplus(W_raw) to d_out tail (runs concurrently;
// nobody reads it — phase C recomputes softplus inline from wraw).
__global__ __launch_bounds__(256)
void k_fused(const float* __restrict__ x,
             const float* __restrict__ mask,
             const float* __restrict__ pw,
             const float* __restrict__ wraw,
             const float* __restrict__ beta,
             float* __restrict__ h,
             float* __restrict__ wout) {
    const int tid  = threadIdx.x;
    const int bn   = blockIdx.x;

    if (bn == BN) {   // W-output block: no barriers, returns early
        for (int i = tid; i < FEAT * D_; i += 256)
            wout[i] = softplusf(wraw[i]);
        return;
    }

    __shared__ float vpart[T_][K_ + 1];   // pad: odd stride, conflict-free
    __shared__ float sf[FEAT];
    __shared__ float ylds[D_];
    __shared__ float smask[T_];

    const int lane = tid & 63;
    const int w    = tid >> 6;
    const int b    = bn / N_;
    const int n    = bn - b * N_;

    // u-slice for this wave's two k's: 6 v4f = 24 VGPRs, loop-invariant
    v4f u[2][3];
#pragma unroll
    for (int kk = 0; kk < 2; kk++)
#pragma unroll
        for (int c = 0; c < 3; c++)
            u[kk][c] = *(const v4f*)(pw + (2 * w + kk) * D_ + c * 256 + lane * 4);

    if (tid < T_) smask[tid] = mask[(b * T_ + tid) * N_ + n];

    // ---- Phase A: all 64 rows, 1-deep prefetch, 2 k's per wave.
    // No periodic barrier: wave skew lets trailing waves hit L1/L2 on the
    // shared rows instead of piling concurrent misses on the MSHRs. ----
    const v4f* x4 = (const v4f*)x;
    unsigned qn = (unsigned)((b * T_) * N_ + n) * QPR;
    v4f n0 = x4[qn + lane];
    v4f n1 = x4[qn + 64 + lane];
    v4f n2 = x4[qn + 128 + lane];
#pragma unroll 1
    for (int t = 0; t < T_; t++) {
        v4f c0 = n0, c1 = n1, c2 = n2;
        if (t < T_ - 1) {
            qn += RSTRIDE;
            n0 = x4[qn + lane];
            n1 = x4[qn + 64 + lane];
            n2 = x4[qn + 128 + lane];
        }
        float a0 = dot4(c0, u[0][0]) + dot4(c1, u[0][1]) + dot4(c2, u[0][2]);
        float a1 = dot4(c0, u[1][0]) + dot4(c1, u[1][1]) + dot4(c2, u[1][2]);
        a0 += __shfl_xor(a0, 1, 64);
        a1 += __shfl_xor(a1, 1, 64);
        float val = (lane & 1) ? a1 : a0;
        val += __shfl_xor(val, 2, 64);
        val += __shfl_xor(val, 4, 64);
        val += __shfl_xor(val, 8, 64);
        val += __shfl_xor(val, 16, 64);
        val += __shfl_xor(val, 32, 64);
        if (lane < 2) vpart[t][2 * w + lane] = val;
    }
    __syncthreads();

    // ---- Phase B: wave w owns k = w and k = w+4; lane = t ----
#pragma unroll
    for (int kk = 0; kk < 2; kk++) {
        const int k = w + kk * 4;
        float v = vpart[lane][k] * smask[lane];
        float s2  = wredux(v * v);
        float rms = sqrtf(s2 * (1.0f / T_) + EPSF);
        float vb  = 2.5f * tanhf(v / (rms + EPSF));
        const float PI = 3.14159265358979323846f;
        float ph = PI * ((float)lane + 0.5f) / (float)T_;
        float c1 = cosf(ph), c2 = cosf(2.0f * ph);
        float n1 = wredux(c1 * c1), n2 = wredux(c2 * c2);
        float S1 = wredux(vb), Sc1 = wredux(vb * c1);
        float Sc2 = wredux(vb * c2), Sq = wredux(vb * vb);
        if (lane == 0) {
            float* o = sf + k * 5;
            o[0] = S1 / (8.0f + EPSF);
            o[1] = Sc1 / (sqrtf(n1) + EPSF);
            o[2] = Sc2 / (sqrtf(n2) + EPSF);
            o[3] = S1 * (1.0f / T_);
            o[4] = sqrtf(Sq * (1.0f / T_) + EPSF);
        }
    }
    __syncthreads();

    // ---- Phase C: ylds[d] = sigmoid(beta[d]) * sum_f sf[f]*softplus(wraw[f][d])
    // (wraw is L2-hot; softplus inline on the mostly-idle VALU) ----
    for (int d = tid; d < D_; d += 256) {
        float a0 = 0.f, a1 = 0.f;
#pragma unroll
        for (int f = 0; f < FEAT; f += 2) {
            a0 += sf[f]     * softplusf(wraw[f * D_ + d]);
            a1 += sf[f + 1] * softplusf(wraw[(f + 1) * D_ + d]);
        }
        float bs = 1.0f / (1.0f + expf(-beta[d]));
        ylds[d] = (a0 + a1) * bs;
    }
    __syncthreads();

    // ---- Phase D: rows t = w*16..w*16+15; 2-row double-buffer;
    // plain x loads (L3-hot — nt hint removed), nt stores for h ----
    const v4f* y4 = (const v4f*)ylds;
    const v4f y0 = y4[lane], y1 = y4[64 + lane], y2 = y4[128 + lane];
    v4f* h4 = (v4f*)h;
    const unsigned qD0 = (unsigned)((b * T_ + w * 16) * N_ + n) * QPR;
    v4f Xa0 = x4[qD0 + lane];
    v4f Xa1 = x4[qD0 + 64 + lane];
    v4f Xa2 = x4[qD0 + 128 + lane];
    v4f Xb0 = x4[qD0 + RSTRIDE + lane];
    v4f Xb1 = x4[qD0 + RSTRIDE + 64 + lane];
    v4f Xb2 = x4[qD0 + RSTRIDE + 128 + lane];
#pragma unroll 1
    for (int j = 0; j < 16; j += 2) {
        const unsigned qa = qD0 + (unsigned)j * RSTRIDE;
        const unsigned qb = qa + RSTRIDE;
        const float ma = smask[w * 16 + j];
        const float mb = smask[w * 16 + j + 1];
        // compute row j into temps, refill Xa with row j+2, then store
        v4f h0 = Xa0 + ma * y0, h1 = Xa1 + ma * y1, h2 = Xa2 + ma * y2;
        if (j + 2 < 16) {
            const unsigned qn2 = qa + 2 * RSTRIDE;
            Xa0 = x4[qn2 + lane];
            Xa1 = x4[qn2 + 64 + lane];
            Xa2 = x4[qn2 + 128 + lane];
        }
        __builtin_nontemporal_store(h0, h4 + qa + lane);
        __builtin_nontemporal_store(h1, h4 + qa + 64 + lane);
        __builtin_nontemporal_store(h2, h4 + qa + 128 + lane);
        // row j+1 from Xb, refill Xb with row j+3, store
        v4f g0 = Xb0 + mb * y0, g1 = Xb1 + mb * y1, g2 = Xb2 + mb * y2;
        if (j + 3 < 16) {
            const unsigned qn3 = qb + 2 * RSTRIDE;
            Xb0 = x4[qn3 + lane];
            Xb1 = x4[qn3 + 64 + lane];
            Xb2 = x4[qn3 + 128 + lane];
        }
        __builtin_nontemporal_store(g0, h4 + qb + lane);
        __builtin_nontemporal_store(g1, h4 + qb + 64 + lane);
        __builtin_nontemporal_store(g2, h4 + qb + 128 + lane);
    }
}

extern "C" void kernel_launch(void* const* d_in, const int* in_sizes, int n_in,
                              void* d_out, int out_size, void* d_ws, size_t ws_size,
                              hipStream_t stream) {
    const float* x    = (const float*)d_in[0];
    const float* mask = (const float*)d_in[1];
    const float* pw   = (const float*)d_in[2];
    const float* wraw = (const float*)d_in[3];
    const float* beta = (const float*)d_in[4];

    float* h    = (float*)d_out;
    float* wout = h + HSIZE;

    hipLaunchKernelGGL(k_fused, dim3(BN + 1), dim3(256), 0, stream,
                       x, mask, pw, wraw, beta, h, wout);
}

// Round 12
// 151.453 us; speedup vs baseline: 2.1370x; 2.1370x over previous
//
#include <hip/hip_runtime.h>
#include <math.h>

#define B_ 8
#define T_ 64
#define N_ 196
#define D_ 768
#define K_ 8
#define FEAT 40
#define EPSF 1e-6f

constexpr int BN = B_ * N_;                        // 1568
constexpr int ROWS = B_ * T_ * N_;                 // 100352
constexpr long long HSIZE = (long long)ROWS * D_;  // 77070336
constexpr int QPR = D_ / 4;                        // 192 float4 per row
constexpr unsigned RSTRIDE = (unsigned)N_ * QPR;   // 37632 v4f per t-step

typedef float v4f __attribute__((ext_vector_type(4)));

__device__ __forceinline__ float wredux(float v) {
#pragma unroll
    for (int off = 32; off > 0; off >>= 1)
        v += __shfl_xor(v, off, 64);
    return v;
}

__device__ __forceinline__ float dot4(v4f a, v4f b) {
    return a.x * b.x + a.y * b.y + a.z * b.z + a.w * b.w;
}

// W = softplus(W_raw) -> d_out tail;  beta_s = sigmoid(beta) -> ws
// (round-11 lesson: NEVER recompute softplus per block — 48M transcendentals)
__global__ __launch_bounds__(256) void k_wsp(const float* __restrict__ wraw,
                                             const float* __restrict__ beta,
                                             float* __restrict__ wout,
                                             float* __restrict__ beta_s) {
    int i = blockIdx.x * blockDim.x + threadIdx.x;
    if (i < FEAT * D_) {
        float xw = wraw[i];
        wout[i] = fmaxf(xw, 0.0f) + log1pf(expf(-fabsf(xw)));
    }
    if (i < D_) beta_s[i] = 1.0f / (1.0f + expf(-beta[i]));
}

// Fused, one block per (b,n), 256 threads = 4 waves.
// Phase A: LDS-staged, double-buffered 4-row tiles. Wave w stages row w of
// the NEXT tile (3 coalesced loads -> regs -> ds_write) while all 4 waves
// compute their 2 k's for the CURRENT tile from LDS. Each x byte crosses
// the vmem pipe exactly ONCE (round-10 limiter: 4x redundant wave reads).
__global__ __launch_bounds__(256)
void k_fused(const float* __restrict__ x,
             const float* __restrict__ mask,
             const float* __restrict__ pw,
             const float* __restrict__ wsp,
             const float* __restrict__ beta_s,
             float* __restrict__ h) {
    __shared__ v4f   xbuf[2][4][QPR];     // 24 KB x tile double-buffer
    __shared__ float vpart[T_][K_ + 1];   // pad: odd stride, conflict-free
    __shared__ float sf[FEAT];
    __shared__ float ylds[D_];
    __shared__ float smask[T_];

    const int tid  = threadIdx.x;
    const int lane = tid & 63;
    const int w    = tid >> 6;
    const int bn   = blockIdx.x;
    const int b    = bn / N_;
    const int n    = bn - b * N_;

    // u-slice for this wave's two k's: 6 v4f = 24 VGPRs, loop-invariant
    v4f u[2][3];
#pragma unroll
    for (int kk = 0; kk < 2; kk++)
#pragma unroll
        for (int c = 0; c < 3; c++)
            u[kk][c] = *(const v4f*)(pw + (2 * w + kk) * D_ + c * 256 + lane * 4);

    if (tid < T_) smask[tid] = mask[(b * T_ + tid) * N_ + n];

    // ---- Phase A: 16 tiles x 4 rows, LDS double-buffered ----
    const v4f* x4 = (const v4f*)x;
    const unsigned TSTRIDE = 4 * RSTRIDE;
    // wave w stages row t = tile*4 + w
    unsigned q = (unsigned)((b * T_ + w) * N_ + n) * QPR;
    v4f R0 = x4[q + lane], R1 = x4[q + 64 + lane], R2 = x4[q + 128 + lane];
    xbuf[0][w][lane]       = R0;
    xbuf[0][w][64 + lane]  = R1;
    xbuf[0][w][128 + lane] = R2;
    __syncthreads();
    int p = 0;
#pragma unroll 1
    for (int tile = 0; tile < 16; ++tile) {
        // prefetch next tile's row w into regs (async under compute)
        if (tile < 15) {
            q += TSTRIDE;
            R0 = x4[q + lane];
            R1 = x4[q + 64 + lane];
            R2 = x4[q + 128 + lane];
        }
        // compute current tile from LDS: 4 rows x 2 k's per wave
#pragma unroll
        for (int r = 0; r < 4; ++r) {
            v4f c0 = xbuf[p][r][lane];
            v4f c1 = xbuf[p][r][64 + lane];
            v4f c2 = xbuf[p][r][128 + lane];
            float a0 = dot4(c0, u[0][0]) + dot4(c1, u[0][1]) + dot4(c2, u[0][2]);
            float a1 = dot4(c0, u[1][0]) + dot4(c1, u[1][1]) + dot4(c2, u[1][2]);
            a0 += __shfl_xor(a0, 1, 64);
            a1 += __shfl_xor(a1, 1, 64);
            float val = (lane & 1) ? a1 : a0;
            val += __shfl_xor(val, 2, 64);
            val += __shfl_xor(val, 4, 64);
            val += __shfl_xor(val, 8, 64);
            val += __shfl_xor(val, 16, 64);
            val += __shfl_xor(val, 32, 64);
            if (lane < 2) vpart[tile * 4 + r][2 * w + lane] = val;
        }
        // write next tile into the other buffer (stalls only on its loads)
        if (tile < 15) {
            xbuf[p ^ 1][w][lane]       = R0;
            xbuf[p ^ 1][w][64 + lane]  = R1;
            xbuf[p ^ 1][w][128 + lane] = R2;
        }
        __syncthreads();   // one barrier/tile: orders reads/writes of both bufs
        p ^= 1;
    }

    // ---- Phase B: wave w owns k = w and k = w+4; lane = t ----
#pragma unroll
    for (int kk = 0; kk < 2; kk++) {
        const int k = w + kk * 4;
        float v = vpart[lane][k] * smask[lane];
        float s2  = wredux(v * v);
        float rms = sqrtf(s2 * (1.0f / T_) + EPSF);
        float vb  = 2.5f * tanhf(v / (rms + EPSF));
        const float PI = 3.14159265358979323846f;
        float ph = PI * ((float)lane + 0.5f) / (float)T_;
        float c1 = cosf(ph), c2 = cosf(2.0f * ph);
        float n1 = wredux(c1 * c1), n2 = wredux(c2 * c2);
        float S1 = wredux(vb), Sc1 = wredux(vb * c1);
        float Sc2 = wredux(vb * c2), Sq = wredux(vb * vb);
        if (lane == 0) {
            float* o = sf + k * 5;
            o[0] = S1 / (8.0f + EPSF);
            o[1] = Sc1 / (sqrtf(n1) + EPSF);
            o[2] = Sc2 / (sqrtf(n2) + EPSF);
            o[3] = S1 * (1.0f / T_);
            o[4] = sqrtf(Sq * (1.0f / T_) + EPSF);
        }
    }
    __syncthreads();

    // ---- Phase C: ylds[d] = beta_s[d] * sum_f sf[f]*wsp[f][d] (L2-hot) ----
    for (int d = tid; d < D_; d += 256) {
        float a0 = 0.f, a1 = 0.f;
#pragma unroll
        for (int f = 0; f < FEAT; f += 2) {
            a0 += sf[f]     * wsp[f * D_ + d];
            a1 += sf[f + 1] * wsp[(f + 1) * D_ + d];
        }
        ylds[d] = (a0 + a1) * beta_s[d];
    }
    __syncthreads();

    // ---- Phase D: rows t = w*16..w*16+15; x reload L3-hot; nt stores ----
    const v4f* y4 = (const v4f*)ylds;
    const v4f y0 = y4[lane], y1 = y4[64 + lane], y2 = y4[128 + lane];
    v4f* h4 = (v4f*)h;
    unsigned qD = (unsigned)((b * T_ + w * 16) * N_ + n) * QPR;
    v4f d0 = __builtin_nontemporal_load(x4 + qD + lane);
    v4f d1 = __builtin_nontemporal_load(x4 + qD + 64 + lane);
    v4f d2 = __builtin_nontemporal_load(x4 + qD + 128 + lane);
#pragma unroll 1
    for (int j = 0; j < 16; j++) {
        v4f c0 = d0, c1 = d1, c2 = d2;
        const unsigned qc = qD;
        if (j < 15) {
            qD += RSTRIDE;
            d0 = __builtin_nontemporal_load(x4 + qD + lane);
            d1 = __builtin_nontemporal_load(x4 + qD + 64 + lane);
            d2 = __builtin_nontemporal_load(x4 + qD + 128 + lane);
        }
        const float m = smask[w * 16 + j];
        __builtin_nontemporal_store(c0 + m * y0, h4 + qc + lane);
        __builtin_nontemporal_store(c1 + m * y1, h4 + qc + 64 + lane);
        __builtin_nontemporal_store(c2 + m * y2, h4 + qc + 128 + lane);
    }
}

extern "C" void kernel_launch(void* const* d_in, const int* in_sizes, int n_in,
                              void* d_out, int out_size, void* d_ws, size_t ws_size,
                              hipStream_t stream) {
    const float* x    = (const float*)d_in[0];
    const float* mask = (const float*)d_in[1];
    const float* pw   = (const float*)d_in[2];
    const float* wraw = (const float*)d_in[3];
    const float* beta = (const float*)d_in[4];

    float* h    = (float*)d_out;
    float* wout = h + HSIZE;
    float* beta_s = (float*)d_ws;   // [768]

    hipLaunchKernelGGL(k_wsp, dim3((FEAT * D_ + 255) / 256), dim3(256), 0, stream,
                       wraw, beta, wout, beta_s);
    hipLaunchKernelGGL(k_fused, dim3(BN), dim3(256), 0, stream,
                       x, mask, pw, wout, beta_s, h);
}